// Round 10
// baseline (164.288 us; speedup 1.0000x reference)
//
#include <hip/hip_runtime.h>

#define LEVEL_DIM 8
#define CDIM 32
#define NCELLS (CDIM*CDIM*CDIM)   // 32768 morton-ordered cells
#define NGROUPS (NCELLS/8)        // 4096 groups of 2x2x2 cells
#define SLAB_ROWS 1307            // 27+64+216+1000 rows * 16B = 20912 B

typedef float    f32x4 __attribute__((ext_vector_type(4)));
typedef unsigned u32x4 __attribute__((ext_vector_type(4)));

__device__ __forceinline__ unsigned part1by2(unsigned x) {
    x &= 0x3ff;
    x = (x | (x << 16)) & 0x030000FF;
    x = (x | (x << 8))  & 0x0300F00F;
    x = (x | (x << 4))  & 0x030C30C3;
    x = (x | (x << 2))  & 0x09249249;
    return x;
}
__device__ __forceinline__ unsigned compact1by2(unsigned x) {
    x &= 0x09249249;
    x = (x | (x >> 2))  & 0x030C30C3;
    x = (x | (x >> 4))  & 0x0300F00F;
    x = (x | (x >> 8))  & 0x030000FF;
    x = (x | (x >> 16)) & 0x000003FF;
    return x;
}

__device__ __forceinline__ int cell_of(float x, float y, float z) {
    int cx = min(CDIM - 1, max(0, (int)(x * (float)CDIM)));
    int cy = min(CDIM - 1, max(0, (int)(y * (float)CDIM)));
    int cz = min(CDIM - 1, max(0, (int)(z * (float)CDIM)));
    return (int)(part1by2(cx) | (part1by2(cy) << 1) | (part1by2(cz) << 2));
}

__device__ __forceinline__ unsigned pk_bf16(float a, float b) {
    unsigned ua = __float_as_uint(a), ub = __float_as_uint(b);
    ua += 0x7fffu + ((ua >> 16) & 1u);
    ub += 0x7fffu + ((ub >> 16) & 1u);
    return (ua >> 16) | (ub & 0xffff0000u);
}

__global__ __launch_bounds__(256) void nv_hist(
    const float* __restrict__ in, int* __restrict__ hist,
    unsigned* __restrict__ cellrank, int B)
{
    const int b = blockIdx.x * 256 + threadIdx.x;
    if (b >= B) return;
    const float x = in[3 * b], y = in[3 * b + 1], z = in[3 * b + 2];
    const int c = cell_of(x, y, z);
    const unsigned r = (unsigned)atomicAdd(&hist[c], 1);
    cellrank[b] = (unsigned)c | (r << 15);
}

__global__ __launch_bounds__(1024) void nv_scan(int* __restrict__ cell)
{
    __shared__ int lds[1024];
    const int tid = threadIdx.x;
    const int base = tid * (NCELLS / 1024);
    int v[NCELLS / 1024];
    int s = 0;
    #pragma unroll
    for (int e = 0; e < NCELLS / 1024; ++e) { v[e] = cell[base + e]; s += v[e]; }
    lds[tid] = s;
    __syncthreads();
    for (int off = 1; off < 1024; off <<= 1) {
        int t = 0;
        if (tid >= off) t = lds[tid - off];
        __syncthreads();
        if (tid >= off) lds[tid] += t;
        __syncthreads();
    }
    int run = lds[tid] - s;
    #pragma unroll
    for (int e = 0; e < NCELLS / 1024; ++e) { cell[base + e] = run; run += v[e]; }
}

__global__ __launch_bounds__(256) void nv_scatter(
    const float* __restrict__ in, const int* __restrict__ starts,
    const unsigned* __restrict__ cellrank, f32x4* __restrict__ sorted, int B)
{
    const int b = blockIdx.x * 256 + threadIdx.x;
    if (b >= B) return;
    const float x = in[3 * b], y = in[3 * b + 1], z = in[3 * b + 2];
    const unsigned cr = cellrank[b];
    const int pos = starts[cr & 0x7fffu] + (int)(cr >> 15);
    f32x4 v = { x, y, z, __uint_as_float((unsigned)b) };
    sorted[pos] = v;
}

template<int R, int S, int BASE, int TOFF>
__device__ __forceinline__ void stage_level(
    const float* __restrict__ emb, unsigned* slab,
    int s0x, int s0y, int s0z, int tid)
{
    const float* tbl = emb + (size_t)TOFF * LEVEL_DIM;
    constexpr int ROWS = S * S * S;
    #pragma unroll
    for (int t0 = 0; t0 < ROWS; t0 += 256) {
        const int t = t0 + tid;
        if (t < ROWS) {
            const int lx = t % S;
            const int tm = t / S;
            const int ly = tm % S;
            const int lz = tm / S;
            const float* src = tbl +
                ((size_t)((s0z + lz) * R + (s0y + ly)) * R + (s0x + lx)) * LEVEL_DIM;
            const f32x4 a = *(const f32x4*)src;
            const f32x4 b = *(const f32x4*)(src + 4);
            u32x4 d = { pk_bf16(a.x, a.y), pk_bf16(a.z, a.w),
                        pk_bf16(b.x, b.y), pk_bf16(b.z, b.w) };
            *(u32x4*)&slab[(BASE + t) * 4] = d;
        }
    }
}

// MODE 0: no store (asm keep-alive)    — isolates loads+gather+VALU
// MODE 1: cached store to out          — tests NT-vs-cached write path
template<int MODE>
__global__ __launch_bounds__(256) void nv_encode_groupT(
    const f32x4* __restrict__ sorted,
    const int* __restrict__ starts,
    const float* __restrict__ emb,
    float* __restrict__ out,
    int B)
{
    __shared__ __align__(16) unsigned slab[SLAB_ROWS * 4];   // 20912 B

    int grp = (int)blockIdx.x;
    grp = (grp & 7) * (NGROUPS / 8) + (grp >> 3);

    const int c0 = grp << 3;
    const int start = starts[c0];
    const int end   = (c0 + 8 < NCELLS) ? starts[c0 + 8] : B;
    if (start >= end) return;

    const int gx = (int)compact1by2((unsigned)grp);
    const int gy = (int)compact1by2((unsigned)grp >> 1);
    const int gz = (int)compact1by2((unsigned)grp >> 2);

    const int s0x0 = min((gx * 30)  >> 5, 13),  s0y0 = min((gy * 30)  >> 5, 13),  s0z0 = min((gz * 30)  >> 5, 13);
    const int s0x1 = min((gx * 62)  >> 5, 28),  s0y1 = min((gy * 62)  >> 5, 28),  s0z1 = min((gz * 62)  >> 5, 28);
    const int s0x2 = min((gx * 126) >> 5, 58),  s0y2 = min((gy * 126) >> 5, 58),  s0z2 = min((gz * 126) >> 5, 58);
    const int s0x3 = min((gx * 254) >> 5, 118), s0y3 = min((gy * 254) >> 5, 118), s0z3 = min((gz * 254) >> 5, 118);

    const int tid = threadIdx.x;
    stage_level<16,  3,  0,   0>     (emb, slab, s0x0, s0y0, s0z0, tid);
    stage_level<32,  4,  27,  4096>  (emb, slab, s0x1, s0y1, s0z1, tid);
    stage_level<64,  6,  91,  36864> (emb, slab, s0x2, s0y2, s0z2, tid);
    stage_level<128, 10, 307, 299008>(emb, slab, s0x3, s0y3, s0z3, tid);
    __syncthreads();

    const int ln  = tid & 7;
    const int lvl = ln >> 1;
    const int sub = tid >> 3;

    #define SEL4(v0,v1,v2,v3) ((lvl & 2) ? ((lvl & 1) ? (v3) : (v2)) \
                                         : ((lvl & 1) ? (v1) : (v0)))
    const float scale = SEL4(15.0f, 31.0f, 63.0f, 127.0f);
    const int   Rm1   = SEL4(15, 31, 63, 127);
    const int   S_    = SEL4(3, 4, 6, 10);
    const int   BASE_ = SEL4(0, 27, 91, 307);
    const int   sx    = SEL4(s0x0, s0x1, s0x2, s0x3);
    const int   sy    = SEL4(s0y0, s0y1, s0y2, s0y3);
    const int   sz    = SEL4(s0z0, s0z1, s0z2, s0z3);
    #undef SEL4
    const int dsel = (ln & 1) * 2;

    for (int p = start + sub; p < end; p += 32) {
        const f32x4 s = sorted[p];
        const unsigned ob = __float_as_uint(s.w);

        const float px = s.x * scale, py = s.y * scale, pz = s.z * scale;
        const float gpx = floorf(px), gpy = floorf(py), gpz = floorf(pz);
        const float fx = px - gpx, fy = py - gpy, fz = pz - gpz;
        const int ix = (int)gpx, iy = (int)gpy, iz = (int)gpz;

        const int ix0 = min(max(ix, 0), Rm1),     ix1 = min(max(ix + 1, 0), Rm1);
        const int iy0 = min(max(iy, 0), Rm1),     iy1 = min(max(iy + 1, 0), Rm1);
        const int iz0 = min(max(iz, 0), Rm1),     iz1 = min(max(iz + 1, 0), Rm1);

        const int lx0 = ix0 - sx, lx1 = ix1 - sx;
        const int ly0 = iy0 - sy, ly1 = iy1 - sy;
        const int lz0 = iz0 - sz, lz1 = iz1 - sz;

        const float wx0 = 1.0f - fx, wx1 = fx;
        const float wy0 = 1.0f - fy, wy1 = fy;
        const float wz0 = 1.0f - fz, wz1 = fz;

        const int rzy00 = BASE_ + (lz0 * S_ + ly0) * S_;
        const int rzy01 = BASE_ + (lz0 * S_ + ly1) * S_;
        const int rzy10 = BASE_ + (lz1 * S_ + ly0) * S_;
        const int rzy11 = BASE_ + (lz1 * S_ + ly1) * S_;

        float a0 = 0.0f, a1 = 0.0f, a2 = 0.0f, a3 = 0.0f;

        #define CORNER(rzy, lx, wx, wy, wz) do {                              \
            const uint2 d = *(const uint2*)&slab[((rzy) + (lx)) * 4 + dsel];  \
            const float w = ((wx) * (wy)) * (wz);                             \
            a0 = fmaf(w, __uint_as_float(d.x << 16),         a0);             \
            a1 = fmaf(w, __uint_as_float(d.x & 0xffff0000u), a1);             \
            a2 = fmaf(w, __uint_as_float(d.y << 16),         a2);             \
            a3 = fmaf(w, __uint_as_float(d.y & 0xffff0000u), a3);             \
        } while (0)

        CORNER(rzy00, lx0, wx0, wy0, wz0);
        CORNER(rzy00, lx1, wx1, wy0, wz0);
        CORNER(rzy01, lx0, wx0, wy1, wz0);
        CORNER(rzy01, lx1, wx1, wy1, wz0);
        CORNER(rzy10, lx0, wx0, wy0, wz1);
        CORNER(rzy10, lx1, wx1, wy0, wz1);
        CORNER(rzy11, lx0, wx0, wy1, wz1);
        CORNER(rzy11, lx1, wx1, wy1, wz1);
        #undef CORNER

        if (MODE == 0) {
            // keep the whole compute chain live without storing
            asm volatile("" :: "v"(a0), "v"(a1), "v"(a2), "v"(a3), "v"(ob));
        } else {
            const f32x4 r = { a0, a1, a2, a3 };
            *(f32x4*)(out + (size_t)ob * 32 + ln * 4) = r;   // cached store
        }
    }
}

// ---- fallback direct kernel (ws too small) ----
__global__ __launch_bounds__(256) void nv_encode_direct(
    const float* __restrict__ in,
    const float* __restrict__ emb,
    float* __restrict__ out,
    int B)
{
    const int i = blockIdx.x * 256 + threadIdx.x;
    if (i >= B) return;
    const float x = in[3 * i], y = in[3 * i + 1], z = in[3 * i + 2];
    float* op = out + (size_t)i * 32;

    const int RES[4] = {16, 32, 64, 128};
    const int OFF[4] = {0, 4096, 36864, 299008};

    #pragma unroll
    for (int l = 0; l < 4; ++l) {
        const int R = RES[l];
        const float scale = (float)(R - 1);
        const float px = x * scale, py = y * scale, pz = z * scale;
        const float gxf = floorf(px), gyf = floorf(py), gzf = floorf(pz);
        const float fx = px - gxf, fy = py - gyf, fz = pz - gzf;
        const int ix = (int)gxf, iy = (int)gyf, iz = (int)gzf;
        const int ix0 = min(max(ix, 0), R - 1), ix1 = min(max(ix + 1, 0), R - 1);
        const int iy0 = min(max(iy, 0), R - 1), iy1 = min(max(iy + 1, 0), R - 1);
        const int iz0 = min(max(iz, 0), R - 1), iz1 = min(max(iz + 1, 0), R - 1);
        const float* tbl = emb + (size_t)OFF[l] * LEVEL_DIM;
        const float wx0 = 1.0f - fx, wx1 = fx;
        float acc[8];
        #pragma unroll
        for (int c = 0; c < 8; ++c) acc[c] = 0.0f;
        #pragma unroll
        for (int kk = 0; kk < 2; ++kk) {
            const int zz = kk ? iz1 : iz0;
            const float wz = kk ? fz : (1.0f - fz);
            #pragma unroll
            for (int jj = 0; jj < 2; ++jj) {
                const int yy = jj ? iy1 : iy0;
                const float wy = jj ? fy : (1.0f - fy);
                const size_t rowbase = ((size_t)zz * R + yy) * (size_t)R;
                const float* r0 = tbl + (rowbase + ix0) * LEVEL_DIM;
                const float* r1 = tbl + (rowbase + ix1) * LEVEL_DIM;
                const float w0 = (wx0 * wy) * wz;
                const float w1 = (wx1 * wy) * wz;
                const float4 a0 = *(const float4*)(r0);
                const float4 a1 = *(const float4*)(r0 + 4);
                const float4 b0 = *(const float4*)(r1);
                const float4 b1 = *(const float4*)(r1 + 4);
                acc[0] = fmaf(w0, a0.x, acc[0]); acc[1] = fmaf(w0, a0.y, acc[1]);
                acc[2] = fmaf(w0, a0.z, acc[2]); acc[3] = fmaf(w0, a0.w, acc[3]);
                acc[4] = fmaf(w0, a1.x, acc[4]); acc[5] = fmaf(w0, a1.y, acc[5]);
                acc[6] = fmaf(w0, a1.z, acc[6]); acc[7] = fmaf(w0, a1.w, acc[7]);
                acc[0] = fmaf(w1, b0.x, acc[0]); acc[1] = fmaf(w1, b0.y, acc[1]);
                acc[2] = fmaf(w1, b0.z, acc[2]); acc[3] = fmaf(w1, b0.w, acc[3]);
                acc[4] = fmaf(w1, b1.x, acc[4]); acc[5] = fmaf(w1, b1.y, acc[5]);
                acc[6] = fmaf(w1, b1.z, acc[6]); acc[7] = fmaf(w1, b1.w, acc[7]);
            }
        }
        *(float4*)(op + l * 8)     = make_float4(acc[0], acc[1], acc[2], acc[3]);
        *(float4*)(op + l * 8 + 4) = make_float4(acc[4], acc[5], acc[6], acc[7]);
    }
}

extern "C" void kernel_launch(void* const* d_in, const int* in_sizes, int n_in,
                              void* d_out, int out_size, void* d_ws, size_t ws_size,
                              hipStream_t stream) {
    const float* in  = (const float*)d_in[0];
    const float* emb = (const float*)d_in[1];
    float* out = (float*)d_out;

    const int B = in_sizes[0] / 3;
    const int block = 256;
    const int grid = (B + block - 1) / block;

    const size_t hist_bytes = (size_t)NCELLS * sizeof(int);
    const size_t rank_bytes = (size_t)B * sizeof(unsigned);
    const size_t need = hist_bytes + rank_bytes + (size_t)B * sizeof(f32x4);

    if (ws_size >= need) {
        int*      hist     = (int*)d_ws;
        unsigned* cellrank = (unsigned*)((char*)d_ws + hist_bytes);
        f32x4*    sorted   = (f32x4*)((char*)d_ws + hist_bytes + rank_bytes);

        (void)hipMemsetAsync(hist, 0, hist_bytes, stream);
        nv_hist<<<grid, block, 0, stream>>>(in, hist, cellrank, B);
        nv_scan<<<1, 1024, 0, stream>>>(hist);
        nv_scatter<<<grid, block, 0, stream>>>(in, hist, cellrank, sorted, B);

        // ABLATION: no-store probe (writes nothing), then the real cached-store pass
        nv_encode_groupT<0><<<NGROUPS, 256, 0, stream>>>(sorted, hist, emb, out, B);
        nv_encode_groupT<1><<<NGROUPS, 256, 0, stream>>>(sorted, hist, emb, out, B);
    } else {
        nv_encode_direct<<<grid, block, 0, stream>>>(in, emb, out, B);
    }
}

// Round 11
// 130.183 us; speedup vs baseline: 1.2620x; 1.2620x over previous
//
#include <hip/hip_runtime.h>

#define LEVEL_DIM 8
#define CDIM 32
#define NCELLS (CDIM*CDIM*CDIM)   // 32768 morton-ordered cells
#define NGROUPS (NCELLS/8)        // 4096 groups of 2x2x2 cells
#define SLAB_ROWS 1307            // 27+64+216+1000 rows * 16B = 20912 B

// workspace layout (bytes)
#define OVF_CAP      65536
#define COUNTS_BYTES (NCELLS * 4)               // 131072
#define OVFCNT_OFF   COUNTS_BYTES               // 131072
#define OVF_OFF      (COUNTS_BYTES + 256)       // 131328
#define BUCKETS_OFF  (OVF_OFF + OVF_CAP * 16)   // 1179904
#define CAP_MIN      36
#define CAP_MAX      64

typedef float    f32x4 __attribute__((ext_vector_type(4)));
typedef unsigned u32x4 __attribute__((ext_vector_type(4)));

__device__ __forceinline__ unsigned part1by2(unsigned x) {
    x &= 0x3ff;
    x = (x | (x << 16)) & 0x030000FF;
    x = (x | (x << 8))  & 0x0300F00F;
    x = (x | (x << 4))  & 0x030C30C3;
    x = (x | (x << 2))  & 0x09249249;
    return x;
}
__device__ __forceinline__ unsigned compact1by2(unsigned x) {
    x &= 0x09249249;
    x = (x | (x >> 2))  & 0x030C30C3;
    x = (x | (x >> 4))  & 0x0300F00F;
    x = (x | (x >> 8))  & 0x030000FF;
    x = (x | (x >> 16)) & 0x000003FF;
    return x;
}

__device__ __forceinline__ int cell_of(float x, float y, float z) {
    int cx = min(CDIM - 1, max(0, (int)(x * (float)CDIM)));
    int cy = min(CDIM - 1, max(0, (int)(y * (float)CDIM)));
    int cz = min(CDIM - 1, max(0, (int)(z * (float)CDIM)));
    return (int)(part1by2(cx) | (part1by2(cy) << 1) | (part1by2(cz) << 2));
}

__device__ __forceinline__ unsigned pk_bf16(float a, float b) {
    unsigned ua = __float_as_uint(a), ub = __float_as_uint(b);
    ua += 0x7fffu + ((ua >> 16) & 1u);
    ub += 0x7fffu + ((ub >> 16) & 1u);
    return (ua >> 16) | (ub & 0xffff0000u);
}

// ---- single-pass bucketing (replaces hist+scan+scatter) ----
__global__ __launch_bounds__(256) void nv_bucket(
    const float* __restrict__ in, int* __restrict__ counts,
    int* __restrict__ ovf_cnt, f32x4* __restrict__ ovf,
    f32x4* __restrict__ buckets, int CAP, int B)
{
    const int b = blockIdx.x * 256 + threadIdx.x;
    if (b >= B) return;
    const float x = in[3 * b], y = in[3 * b + 1], z = in[3 * b + 2];
    const int c = cell_of(x, y, z);
    const int r = atomicAdd(&counts[c], 1);
    f32x4 v = { x, y, z, __uint_as_float((unsigned)b) };
    if (r < CAP) {
        buckets[(size_t)c * CAP + r] = v;
    } else {
        const int o = atomicAdd(ovf_cnt, 1);
        if (o < OVF_CAP) ovf[o] = v;
    }
}

// ---- slab staging (bf16-packed rows) ----
template<int R, int S, int BASE, int TOFF>
__device__ __forceinline__ void stage_level(
    const float* __restrict__ emb, unsigned* slab,
    int s0x, int s0y, int s0z, int tid)
{
    const float* tbl = emb + (size_t)TOFF * LEVEL_DIM;
    constexpr int ROWS = S * S * S;
    #pragma unroll
    for (int t0 = 0; t0 < ROWS; t0 += 256) {
        const int t = t0 + tid;
        if (t < ROWS) {
            const int lx = t % S;
            const int tm = t / S;
            const int ly = tm % S;
            const int lz = tm / S;
            const float* src = tbl +
                ((size_t)((s0z + lz) * R + (s0y + ly)) * R + (s0x + lx)) * LEVEL_DIM;
            const f32x4 a = *(const f32x4*)src;
            const f32x4 b = *(const f32x4*)(src + 4);
            u32x4 d = { pk_bf16(a.x, a.y), pk_bf16(a.z, a.w),
                        pk_bf16(b.x, b.y), pk_bf16(b.z, b.w) };
            *(u32x4*)&slab[(BASE + t) * 4] = d;
        }
    }
}

// ---- group encode: 8 lanes/point, padded-bucket input, NT 128B-row store ----
__global__ __launch_bounds__(256) void nv_encode_bucket(
    const f32x4* __restrict__ buckets,
    const int* __restrict__ counts,
    const float* __restrict__ emb,
    float* __restrict__ out,
    int CAP, int B)
{
    __shared__ __align__(16) unsigned slab[SLAB_ROWS * 4];   // 20912 B

    // XCD swizzle: each XCD gets a contiguous morton octant of groups
    int grp = (int)blockIdx.x;
    grp = (grp & 7) * (NGROUPS / 8) + (grp >> 3);
    const int c0 = grp << 3;

    // per-group clamped counts -> running prefix (named regs, no arrays)
    const int cw0 = min(counts[c0 + 0], CAP);
    const int cw1 = min(counts[c0 + 1], CAP);
    const int cw2 = min(counts[c0 + 2], CAP);
    const int cw3 = min(counts[c0 + 3], CAP);
    const int cw4 = min(counts[c0 + 4], CAP);
    const int cw5 = min(counts[c0 + 5], CAP);
    const int cw6 = min(counts[c0 + 6], CAP);
    const int cw7 = min(counts[c0 + 7], CAP);
    const int pf1 = cw0,       pf2 = pf1 + cw1, pf3 = pf2 + cw2, pf4 = pf3 + cw3;
    const int pf5 = pf4 + cw4, pf6 = pf5 + cw5, pf7 = pf6 + cw6;
    const int total = pf7 + cw7;
    if (total == 0) return;

    const int gx = (int)compact1by2((unsigned)grp);
    const int gy = (int)compact1by2((unsigned)grp >> 1);
    const int gz = (int)compact1by2((unsigned)grp >> 2);

    // slab bases per level: s0 = min((2g*(R-1))>>5, R-S)
    const int s0x0 = min((gx * 30)  >> 5, 13),  s0y0 = min((gy * 30)  >> 5, 13),  s0z0 = min((gz * 30)  >> 5, 13);
    const int s0x1 = min((gx * 62)  >> 5, 28),  s0y1 = min((gy * 62)  >> 5, 28),  s0z1 = min((gz * 62)  >> 5, 28);
    const int s0x2 = min((gx * 126) >> 5, 58),  s0y2 = min((gy * 126) >> 5, 58),  s0z2 = min((gz * 126) >> 5, 58);
    const int s0x3 = min((gx * 254) >> 5, 118), s0y3 = min((gy * 254) >> 5, 118), s0z3 = min((gz * 254) >> 5, 118);

    const int tid = threadIdx.x;
    stage_level<16,  3,  0,   0>     (emb, slab, s0x0, s0y0, s0z0, tid);
    stage_level<32,  4,  27,  4096>  (emb, slab, s0x1, s0y1, s0z1, tid);
    stage_level<64,  6,  91,  36864> (emb, slab, s0x2, s0y2, s0z2, tid);
    stage_level<128, 10, 307, 299008>(emb, slab, s0x3, s0y3, s0z3, tid);
    __syncthreads();

    // 8 lanes per point: lane ln owns level ln>>1, channels (ln&1)*4..+4.
    const int ln  = tid & 7;
    const int lvl = ln >> 1;
    const int sub = tid >> 3;          // 0..31: point slot per block pass

    #define SEL4(v0,v1,v2,v3) ((lvl & 2) ? ((lvl & 1) ? (v3) : (v2)) \
                                         : ((lvl & 1) ? (v1) : (v0)))
    const float scale = SEL4(15.0f, 31.0f, 63.0f, 127.0f);
    const int   Rm1   = SEL4(15, 31, 63, 127);
    const int   S_    = SEL4(3, 4, 6, 10);
    const int   BASE_ = SEL4(0, 27, 91, 307);
    const int   sx    = SEL4(s0x0, s0x1, s0x2, s0x3);
    const int   sy    = SEL4(s0y0, s0y1, s0y2, s0y3);
    const int   sz    = SEL4(s0z0, s0z1, s0z2, s0z3);
    #undef SEL4
    const int dsel = (ln & 1) * 2;

    for (int q = sub; q < total; q += 32) {
        // select (cell k, idx) from running prefix — pure cndmask chain
        int k = 0, pfk = 0;
        if (q >= pf1) { k = 1; pfk = pf1; }
        if (q >= pf2) { k = 2; pfk = pf2; }
        if (q >= pf3) { k = 3; pfk = pf3; }
        if (q >= pf4) { k = 4; pfk = pf4; }
        if (q >= pf5) { k = 5; pfk = pf5; }
        if (q >= pf6) { k = 6; pfk = pf6; }
        if (q >= pf7) { k = 7; pfk = pf7; }
        const int idx = q - pfk;

        const f32x4 s = buckets[(size_t)(c0 + k) * CAP + idx];
        const unsigned ob = __float_as_uint(s.w);

        const float px = s.x * scale, py = s.y * scale, pz = s.z * scale;
        const float gpx = floorf(px), gpy = floorf(py), gpz = floorf(pz);
        const float fx = px - gpx, fy = py - gpy, fz = pz - gpz;
        const int ix = (int)gpx, iy = (int)gpy, iz = (int)gpz;

        const int ix0 = min(max(ix, 0), Rm1),     ix1 = min(max(ix + 1, 0), Rm1);
        const int iy0 = min(max(iy, 0), Rm1),     iy1 = min(max(iy + 1, 0), Rm1);
        const int iz0 = min(max(iz, 0), Rm1),     iz1 = min(max(iz + 1, 0), Rm1);

        const int lx0 = ix0 - sx, lx1 = ix1 - sx;
        const int ly0 = iy0 - sy, ly1 = iy1 - sy;
        const int lz0 = iz0 - sz, lz1 = iz1 - sz;

        const float wx0 = 1.0f - fx, wx1 = fx;
        const float wy0 = 1.0f - fy, wy1 = fy;
        const float wz0 = 1.0f - fz, wz1 = fz;

        const int rzy00 = BASE_ + (lz0 * S_ + ly0) * S_;
        const int rzy01 = BASE_ + (lz0 * S_ + ly1) * S_;
        const int rzy10 = BASE_ + (lz1 * S_ + ly0) * S_;
        const int rzy11 = BASE_ + (lz1 * S_ + ly1) * S_;

        float a0 = 0.0f, a1 = 0.0f, a2 = 0.0f, a3 = 0.0f;

        // corner order matches reference CORNERS (x fastest); weights ((wx*wy)*wz)
        #define CORNER(rzy, lx, wx, wy, wz) do {                              \
            const uint2 d = *(const uint2*)&slab[((rzy) + (lx)) * 4 + dsel];  \
            const float w = ((wx) * (wy)) * (wz);                             \
            a0 = fmaf(w, __uint_as_float(d.x << 16),         a0);             \
            a1 = fmaf(w, __uint_as_float(d.x & 0xffff0000u), a1);             \
            a2 = fmaf(w, __uint_as_float(d.y << 16),         a2);             \
            a3 = fmaf(w, __uint_as_float(d.y & 0xffff0000u), a3);             \
        } while (0)

        CORNER(rzy00, lx0, wx0, wy0, wz0);
        CORNER(rzy00, lx1, wx1, wy0, wz0);
        CORNER(rzy01, lx0, wx0, wy1, wz0);
        CORNER(rzy01, lx1, wx1, wy1, wz0);
        CORNER(rzy10, lx0, wx0, wy0, wz1);
        CORNER(rzy10, lx1, wx1, wy0, wz1);
        CORNER(rzy11, lx0, wx0, wy1, wz1);
        CORNER(rzy11, lx1, wx1, wy1, wz1);
        #undef CORNER

        const f32x4 r = { a0, a1, a2, a3 };
        __builtin_nontemporal_store(
            r, (f32x4*)(out + (size_t)ob * 32 + ln * 4));
    }
}

// ---- exact f32 single-point encode (fixup + fallback) ----
__device__ __forceinline__ void encode_point_direct(
    float x, float y, float z, const float* __restrict__ emb, float* op)
{
    const int RES[4] = {16, 32, 64, 128};
    const int OFF[4] = {0, 4096, 36864, 299008};

    #pragma unroll
    for (int l = 0; l < 4; ++l) {
        const int R = RES[l];
        const float scale = (float)(R - 1);
        const float px = x * scale, py = y * scale, pz = z * scale;
        const float gxf = floorf(px), gyf = floorf(py), gzf = floorf(pz);
        const float fx = px - gxf, fy = py - gyf, fz = pz - gzf;
        const int ix = (int)gxf, iy = (int)gyf, iz = (int)gzf;
        const int ix0 = min(max(ix, 0), R - 1), ix1 = min(max(ix + 1, 0), R - 1);
        const int iy0 = min(max(iy, 0), R - 1), iy1 = min(max(iy + 1, 0), R - 1);
        const int iz0 = min(max(iz, 0), R - 1), iz1 = min(max(iz + 1, 0), R - 1);
        const float* tbl = emb + (size_t)OFF[l] * LEVEL_DIM;
        const float wx0 = 1.0f - fx, wx1 = fx;
        float acc[8];
        #pragma unroll
        for (int c = 0; c < 8; ++c) acc[c] = 0.0f;
        #pragma unroll
        for (int kk = 0; kk < 2; ++kk) {
            const int zz = kk ? iz1 : iz0;
            const float wz = kk ? fz : (1.0f - fz);
            #pragma unroll
            for (int jj = 0; jj < 2; ++jj) {
                const int yy = jj ? iy1 : iy0;
                const float wy = jj ? fy : (1.0f - fy);
                const size_t rowbase = ((size_t)zz * R + yy) * (size_t)R;
                const float* r0 = tbl + (rowbase + ix0) * LEVEL_DIM;
                const float* r1 = tbl + (rowbase + ix1) * LEVEL_DIM;
                const float w0 = (wx0 * wy) * wz;
                const float w1 = (wx1 * wy) * wz;
                const float4 a0 = *(const float4*)(r0);
                const float4 a1 = *(const float4*)(r0 + 4);
                const float4 b0 = *(const float4*)(r1);
                const float4 b1 = *(const float4*)(r1 + 4);
                acc[0] = fmaf(w0, a0.x, acc[0]); acc[1] = fmaf(w0, a0.y, acc[1]);
                acc[2] = fmaf(w0, a0.z, acc[2]); acc[3] = fmaf(w0, a0.w, acc[3]);
                acc[4] = fmaf(w0, a1.x, acc[4]); acc[5] = fmaf(w0, a1.y, acc[5]);
                acc[6] = fmaf(w0, a1.z, acc[6]); acc[7] = fmaf(w0, a1.w, acc[7]);
                acc[0] = fmaf(w1, b0.x, acc[0]); acc[1] = fmaf(w1, b0.y, acc[1]);
                acc[2] = fmaf(w1, b0.z, acc[2]); acc[3] = fmaf(w1, b0.w, acc[3]);
                acc[4] = fmaf(w1, b1.x, acc[4]); acc[5] = fmaf(w1, b1.y, acc[5]);
                acc[6] = fmaf(w1, b1.z, acc[6]); acc[7] = fmaf(w1, b1.w, acc[7]);
            }
        }
        *(float4*)(op + l * 8)     = make_float4(acc[0], acc[1], acc[2], acc[3]);
        *(float4*)(op + l * 8 + 4) = make_float4(acc[4], acc[5], acc[6], acc[7]);
    }
}

__global__ __launch_bounds__(256) void nv_fixup(
    const int* __restrict__ ovf_cnt, const f32x4* __restrict__ ovf,
    const float* __restrict__ emb, float* __restrict__ out)
{
    const int n = min(*ovf_cnt, OVF_CAP);
    for (int i = blockIdx.x * 256 + threadIdx.x; i < n; i += gridDim.x * 256) {
        const f32x4 s = ovf[i];
        encode_point_direct(s.x, s.y, s.z, emb,
                            out + (size_t)__float_as_uint(s.w) * 32);
    }
}

__global__ __launch_bounds__(256) void nv_encode_direct(
    const float* __restrict__ in,
    const float* __restrict__ emb,
    float* __restrict__ out,
    int B)
{
    const int i = blockIdx.x * 256 + threadIdx.x;
    if (i >= B) return;
    encode_point_direct(in[3 * i], in[3 * i + 1], in[3 * i + 2],
                        emb, out + (size_t)i * 32);
}

extern "C" void kernel_launch(void* const* d_in, const int* in_sizes, int n_in,
                              void* d_out, int out_size, void* d_ws, size_t ws_size,
                              hipStream_t stream) {
    const float* in  = (const float*)d_in[0];
    const float* emb = (const float*)d_in[1];
    float* out = (float*)d_out;

    const int B = in_sizes[0] / 3;
    const int block = 256;
    const int grid = (B + block - 1) / block;

    const size_t need = (size_t)BUCKETS_OFF + (size_t)CAP_MIN * NCELLS * 16;

    if (ws_size >= need) {
        int CAP = (int)((ws_size - BUCKETS_OFF) / ((size_t)NCELLS * 16));
        if (CAP > CAP_MAX) CAP = CAP_MAX;

        int*   counts  = (int*)d_ws;
        int*   ovf_cnt = (int*)((char*)d_ws + OVFCNT_OFF);
        f32x4* ovf     = (f32x4*)((char*)d_ws + OVF_OFF);
        f32x4* buckets = (f32x4*)((char*)d_ws + BUCKETS_OFF);

        (void)hipMemsetAsync(d_ws, 0, OVF_OFF, stream);   // counts + ovf_cnt
        nv_bucket<<<grid, block, 0, stream>>>(in, counts, ovf_cnt, ovf, buckets, CAP, B);
        nv_encode_bucket<<<NGROUPS, block, 0, stream>>>(buckets, counts, emb, out, CAP, B);
        nv_fixup<<<128, block, 0, stream>>>(ovf_cnt, ovf, emb, out);
    } else {
        nv_encode_direct<<<grid, block, 0, stream>>>(in, emb, out, B);
    }
}

// Round 12
// 122.763 us; speedup vs baseline: 1.3382x; 1.0604x over previous
//
#include <hip/hip_runtime.h>

#define LEVEL_DIM 8
#define CDIM 32
#define NCELLS (CDIM*CDIM*CDIM)   // 32768 morton-ordered cells
#define NGROUPS (NCELLS/8)        // 4096 groups of 2x2x2 cells
#define SLAB_ROWS 1307            // 27+64+216+1000 rows * 16B = 20912 B

typedef float    f32x4 __attribute__((ext_vector_type(4)));
typedef unsigned u32x4 __attribute__((ext_vector_type(4)));

__device__ __forceinline__ unsigned part1by2(unsigned x) {
    x &= 0x3ff;
    x = (x | (x << 16)) & 0x030000FF;
    x = (x | (x << 8))  & 0x0300F00F;
    x = (x | (x << 4))  & 0x030C30C3;
    x = (x | (x << 2))  & 0x09249249;
    return x;
}
__device__ __forceinline__ unsigned compact1by2(unsigned x) {
    x &= 0x09249249;
    x = (x | (x >> 2))  & 0x030C30C3;
    x = (x | (x >> 4))  & 0x0300F00F;
    x = (x | (x >> 8))  & 0x030000FF;
    x = (x | (x >> 16)) & 0x000003FF;
    return x;
}

__device__ __forceinline__ int cell_of(float x, float y, float z) {
    int cx = min(CDIM - 1, max(0, (int)(x * (float)CDIM)));
    int cy = min(CDIM - 1, max(0, (int)(y * (float)CDIM)));
    int cz = min(CDIM - 1, max(0, (int)(z * (float)CDIM)));
    return (int)(part1by2(cx) | (part1by2(cy) << 1) | (part1by2(cz) << 2));
}

// round-to-nearest-even f32 -> bf16, two packed into one dword (a=lo, b=hi)
__device__ __forceinline__ unsigned pk_bf16(float a, float b) {
    unsigned ua = __float_as_uint(a), ub = __float_as_uint(b);
    ua += 0x7fffu + ((ua >> 16) & 1u);
    ub += 0x7fffu + ((ub >> 16) & 1u);
    return (ua >> 16) | (ub & 0xffff0000u);
}

__global__ __launch_bounds__(256) void nv_hist(
    const float* __restrict__ in, int* __restrict__ hist,
    unsigned* __restrict__ cellrank, int B)
{
    const int b = blockIdx.x * 256 + threadIdx.x;
    if (b >= B) return;
    const float x = in[3 * b], y = in[3 * b + 1], z = in[3 * b + 2];
    const int c = cell_of(x, y, z);
    const unsigned r = (unsigned)atomicAdd(&hist[c], 1);
    cellrank[b] = (unsigned)c | (r << 15);     // rank < 2^17 (avg 32/cell)
}

// in-place exclusive scan of NCELLS ints, single workgroup
__global__ __launch_bounds__(1024) void nv_scan(int* __restrict__ cell)
{
    __shared__ int lds[1024];
    const int tid = threadIdx.x;
    const int base = tid * (NCELLS / 1024);
    int v[NCELLS / 1024];
    int s = 0;
    #pragma unroll
    for (int e = 0; e < NCELLS / 1024; ++e) { v[e] = cell[base + e]; s += v[e]; }
    lds[tid] = s;
    __syncthreads();
    for (int off = 1; off < 1024; off <<= 1) {
        int t = 0;
        if (tid >= off) t = lds[tid - off];
        __syncthreads();
        if (tid >= off) lds[tid] += t;
        __syncthreads();
    }
    int run = lds[tid] - s;
    #pragma unroll
    for (int e = 0; e < NCELLS / 1024; ++e) { cell[base + e] = run; run += v[e]; }
}

__global__ __launch_bounds__(256) void nv_scatter(
    const float* __restrict__ in, const int* __restrict__ starts,
    const unsigned* __restrict__ cellrank, f32x4* __restrict__ sorted, int B)
{
    const int b = blockIdx.x * 256 + threadIdx.x;
    if (b >= B) return;
    const float x = in[3 * b], y = in[3 * b + 1], z = in[3 * b + 2];
    const unsigned cr = cellrank[b];
    const int pos = starts[cr & 0x7fffu] + (int)(cr >> 15);
    f32x4 v = { x, y, z, __uint_as_float((unsigned)b) };
    sorted[pos] = v;   // cached store: L2 write-combining, encode re-reads it
}

// ---- slab staging (bf16-packed rows) ----
template<int R, int S, int BASE, int TOFF>
__device__ __forceinline__ void stage_level(
    const float* __restrict__ emb, unsigned* slab,
    int s0x, int s0y, int s0z, int tid)
{
    const float* tbl = emb + (size_t)TOFF * LEVEL_DIM;
    constexpr int ROWS = S * S * S;
    #pragma unroll
    for (int t0 = 0; t0 < ROWS; t0 += 256) {
        const int t = t0 + tid;
        if (t < ROWS) {
            const int lx = t % S;
            const int tm = t / S;
            const int ly = tm % S;
            const int lz = tm / S;
            const float* src = tbl +
                ((size_t)((s0z + lz) * R + (s0y + ly)) * R + (s0x + lx)) * LEVEL_DIM;
            const f32x4 a = *(const f32x4*)src;
            const f32x4 b = *(const f32x4*)(src + 4);
            u32x4 d = { pk_bf16(a.x, a.y), pk_bf16(a.z, a.w),
                        pk_bf16(b.x, b.y), pk_bf16(b.z, b.w) };
            *(u32x4*)&slab[(BASE + t) * 4] = d;
        }
    }
}

// ---- group encode: 8 lanes/point, prefetched point load, NT 128B-row store ----
__global__ __launch_bounds__(256) void nv_encode_group(
    const f32x4* __restrict__ sorted,
    const int* __restrict__ starts,     // exclusive cell starts (unmutated)
    const float* __restrict__ emb,
    float* __restrict__ out,
    int B)
{
    __shared__ __align__(16) unsigned slab[SLAB_ROWS * 4];   // 20912 B

    // XCD swizzle: each XCD gets a contiguous morton octant of groups
    int grp = (int)blockIdx.x;
    grp = (grp & 7) * (NGROUPS / 8) + (grp >> 3);

    const int c0 = grp << 3;
    const int start = starts[c0];
    const int end   = (c0 + 8 < NCELLS) ? starts[c0 + 8] : B;
    if (start >= end) return;

    const int gx = (int)compact1by2((unsigned)grp);
    const int gy = (int)compact1by2((unsigned)grp >> 1);
    const int gz = (int)compact1by2((unsigned)grp >> 2);

    // slab bases per level: s0 = min((2g*(R-1))>>5, R-S)
    const int s0x0 = min((gx * 30)  >> 5, 13),  s0y0 = min((gy * 30)  >> 5, 13),  s0z0 = min((gz * 30)  >> 5, 13);
    const int s0x1 = min((gx * 62)  >> 5, 28),  s0y1 = min((gy * 62)  >> 5, 28),  s0z1 = min((gz * 62)  >> 5, 28);
    const int s0x2 = min((gx * 126) >> 5, 58),  s0y2 = min((gy * 126) >> 5, 58),  s0z2 = min((gz * 126) >> 5, 58);
    const int s0x3 = min((gx * 254) >> 5, 118), s0y3 = min((gy * 254) >> 5, 118), s0z3 = min((gz * 254) >> 5, 118);

    const int tid = threadIdx.x;
    stage_level<16,  3,  0,   0>     (emb, slab, s0x0, s0y0, s0z0, tid);
    stage_level<32,  4,  27,  4096>  (emb, slab, s0x1, s0y1, s0z1, tid);
    stage_level<64,  6,  91,  36864> (emb, slab, s0x2, s0y2, s0z2, tid);
    stage_level<128, 10, 307, 299008>(emb, slab, s0x3, s0y3, s0z3, tid);
    __syncthreads();

    // 8 lanes per point: lane ln owns level ln>>1, channels (ln&1)*4..+4.
    const int ln  = tid & 7;
    const int lvl = ln >> 1;
    const int sub = tid >> 3;          // 0..31: point slot per block pass

    #define SEL4(v0,v1,v2,v3) ((lvl & 2) ? ((lvl & 1) ? (v3) : (v2)) \
                                         : ((lvl & 1) ? (v1) : (v0)))
    const float scale = SEL4(15.0f, 31.0f, 63.0f, 127.0f);
    const int   Rm1   = SEL4(15, 31, 63, 127);
    const int   S_    = SEL4(3, 4, 6, 10);
    const int   BASE_ = SEL4(0, 27, 91, 307);
    const int   sx    = SEL4(s0x0, s0x1, s0x2, s0x3);
    const int   sy    = SEL4(s0y0, s0y1, s0y2, s0y3);
    const int   sz    = SEL4(s0z0, s0z1, s0z2, s0z3);
    #undef SEL4
    const int dsel = (ln & 1) * 2;

    int p = start + sub;
    if (p >= end) return;
    f32x4 s = sorted[p];

    while (p < end) {
        // PREFETCH next point BEFORE this point's store: keeps the NT store
        // out of the next iteration's load-use s_waitcnt (stores stay in flight)
        const int pn = p + 32;
        f32x4 sn = s;
        if (pn < end) sn = sorted[pn];

        const unsigned ob = __float_as_uint(s.w);

        const float px = s.x * scale, py = s.y * scale, pz = s.z * scale;
        const float gpx = floorf(px), gpy = floorf(py), gpz = floorf(pz);
        const float fx = px - gpx, fy = py - gpy, fz = pz - gpz;
        const int ix = (int)gpx, iy = (int)gpy, iz = (int)gpz;

        const int ix0 = min(max(ix, 0), Rm1),     ix1 = min(max(ix + 1, 0), Rm1);
        const int iy0 = min(max(iy, 0), Rm1),     iy1 = min(max(iy + 1, 0), Rm1);
        const int iz0 = min(max(iz, 0), Rm1),     iz1 = min(max(iz + 1, 0), Rm1);

        const int lx0 = ix0 - sx, lx1 = ix1 - sx;
        const int ly0 = iy0 - sy, ly1 = iy1 - sy;
        const int lz0 = iz0 - sz, lz1 = iz1 - sz;

        const float wx0 = 1.0f - fx, wx1 = fx;
        const float wy0 = 1.0f - fy, wy1 = fy;
        const float wz0 = 1.0f - fz, wz1 = fz;

        const int rzy00 = BASE_ + (lz0 * S_ + ly0) * S_;
        const int rzy01 = BASE_ + (lz0 * S_ + ly1) * S_;
        const int rzy10 = BASE_ + (lz1 * S_ + ly0) * S_;
        const int rzy11 = BASE_ + (lz1 * S_ + ly1) * S_;

        float a0 = 0.0f, a1 = 0.0f, a2 = 0.0f, a3 = 0.0f;

        // corner order matches reference CORNERS (x fastest); weights ((wx*wy)*wz)
        #define CORNER(rzy, lx, wx, wy, wz) do {                              \
            const uint2 d = *(const uint2*)&slab[((rzy) + (lx)) * 4 + dsel];  \
            const float w = ((wx) * (wy)) * (wz);                             \
            a0 = fmaf(w, __uint_as_float(d.x << 16),         a0);             \
            a1 = fmaf(w, __uint_as_float(d.x & 0xffff0000u), a1);             \
            a2 = fmaf(w, __uint_as_float(d.y << 16),         a2);             \
            a3 = fmaf(w, __uint_as_float(d.y & 0xffff0000u), a3);             \
        } while (0)

        CORNER(rzy00, lx0, wx0, wy0, wz0);
        CORNER(rzy00, lx1, wx1, wy0, wz0);
        CORNER(rzy01, lx0, wx0, wy1, wz0);
        CORNER(rzy01, lx1, wx1, wy1, wz0);
        CORNER(rzy10, lx0, wx0, wy0, wz1);
        CORNER(rzy10, lx1, wx1, wy0, wz1);
        CORNER(rzy11, lx0, wx0, wy1, wz1);
        CORNER(rzy11, lx1, wx1, wy1, wz1);
        #undef CORNER

        const f32x4 r = { a0, a1, a2, a3 };
        __builtin_nontemporal_store(
            r, (f32x4*)(out + (size_t)ob * 32 + ln * 4));

        s = sn;
        p = pn;
    }
}

// ---- fallback direct kernel (ws too small) ----
__global__ __launch_bounds__(256) void nv_encode_direct(
    const float* __restrict__ in,
    const float* __restrict__ emb,
    float* __restrict__ out,
    int B)
{
    const int i = blockIdx.x * 256 + threadIdx.x;
    if (i >= B) return;
    const float x = in[3 * i], y = in[3 * i + 1], z = in[3 * i + 2];
    float* op = out + (size_t)i * 32;

    const int RES[4] = {16, 32, 64, 128};
    const int OFF[4] = {0, 4096, 36864, 299008};

    #pragma unroll
    for (int l = 0; l < 4; ++l) {
        const int R = RES[l];
        const float scale = (float)(R - 1);
        const float px = x * scale, py = y * scale, pz = z * scale;
        const float gxf = floorf(px), gyf = floorf(py), gzf = floorf(pz);
        const float fx = px - gxf, fy = py - gyf, fz = pz - gzf;
        const int ix = (int)gxf, iy = (int)gyf, iz = (int)gzf;
        const int ix0 = min(max(ix, 0), R - 1), ix1 = min(max(ix + 1, 0), R - 1);
        const int iy0 = min(max(iy, 0), R - 1), iy1 = min(max(iy + 1, 0), R - 1);
        const int iz0 = min(max(iz, 0), R - 1), iz1 = min(max(iz + 1, 0), R - 1);
        const float* tbl = emb + (size_t)OFF[l] * LEVEL_DIM;
        const float wx0 = 1.0f - fx, wx1 = fx;
        float acc[8];
        #pragma unroll
        for (int c = 0; c < 8; ++c) acc[c] = 0.0f;
        #pragma unroll
        for (int kk = 0; kk < 2; ++kk) {
            const int zz = kk ? iz1 : iz0;
            const float wz = kk ? fz : (1.0f - fz);
            #pragma unroll
            for (int jj = 0; jj < 2; ++jj) {
                const int yy = jj ? iy1 : iy0;
                const float wy = jj ? fy : (1.0f - fy);
                const size_t rowbase = ((size_t)zz * R + yy) * (size_t)R;
                const float* r0 = tbl + (rowbase + ix0) * LEVEL_DIM;
                const float* r1 = tbl + (rowbase + ix1) * LEVEL_DIM;
                const float w0 = (wx0 * wy) * wz;
                const float w1 = (wx1 * wy) * wz;
                const float4 a0 = *(const float4*)(r0);
                const float4 a1 = *(const float4*)(r0 + 4);
                const float4 b0 = *(const float4*)(r1);
                const float4 b1 = *(const float4*)(r1 + 4);
                acc[0] = fmaf(w0, a0.x, acc[0]); acc[1] = fmaf(w0, a0.y, acc[1]);
                acc[2] = fmaf(w0, a0.z, acc[2]); acc[3] = fmaf(w0, a0.w, acc[3]);
                acc[4] = fmaf(w0, a1.x, acc[4]); acc[5] = fmaf(w0, a1.y, acc[5]);
                acc[6] = fmaf(w0, a1.z, acc[6]); acc[7] = fmaf(w0, a1.w, acc[7]);
                acc[0] = fmaf(w1, b0.x, acc[0]); acc[1] = fmaf(w1, b0.y, acc[1]);
                acc[2] = fmaf(w1, b0.z, acc[2]); acc[3] = fmaf(w1, b0.w, acc[3]);
                acc[4] = fmaf(w1, b1.x, acc[4]); acc[5] = fmaf(w1, b1.y, acc[5]);
                acc[6] = fmaf(w1, b1.z, acc[6]); acc[7] = fmaf(w1, b1.w, acc[7]);
            }
        }
        *(float4*)(op + l * 8)     = make_float4(acc[0], acc[1], acc[2], acc[3]);
        *(float4*)(op + l * 8 + 4) = make_float4(acc[4], acc[5], acc[6], acc[7]);
    }
}

extern "C" void kernel_launch(void* const* d_in, const int* in_sizes, int n_in,
                              void* d_out, int out_size, void* d_ws, size_t ws_size,
                              hipStream_t stream) {
    const float* in  = (const float*)d_in[0];
    const float* emb = (const float*)d_in[1];
    float* out = (float*)d_out;

    const int B = in_sizes[0] / 3;
    const int block = 256;
    const int grid = (B + block - 1) / block;

    const size_t hist_bytes = (size_t)NCELLS * sizeof(int);        // 128 KiB
    const size_t rank_bytes = (size_t)B * sizeof(unsigned);        // 4 MiB
    const size_t need = hist_bytes + rank_bytes + (size_t)B * sizeof(f32x4);

    if (ws_size >= need) {
        int*      hist     = (int*)d_ws;                                  // -> starts after scan
        unsigned* cellrank = (unsigned*)((char*)d_ws + hist_bytes);
        f32x4*    sorted   = (f32x4*)((char*)d_ws + hist_bytes + rank_bytes);

        (void)hipMemsetAsync(hist, 0, hist_bytes, stream);
        nv_hist<<<grid, block, 0, stream>>>(in, hist, cellrank, B);
        nv_scan<<<1, 1024, 0, stream>>>(hist);
        nv_scatter<<<grid, block, 0, stream>>>(in, hist, cellrank, sorted, B);
        nv_encode_group<<<NGROUPS, block, 0, stream>>>(sorted, hist, emb, out, B);
    } else {
        nv_encode_direct<<<grid, block, 0, stream>>>(in, emb, out, B);
    }
}